// Round 5
// baseline (12957.613 us; speedup 1.0000x reference)
//
#include <hip/hip_runtime.h>
#include <hip/hip_bf16.h>

// MomentumDecoder: 2-layer LSTM (B=512,H=512), 256 autoregressive steps.
// Round 5: gate-pair wave layout (A-reads /2), ds_add gate reduce,
// row-interleaved staging with counted-vmcnt mini-phases, deferred bias.
// 256 WGs x 512 thr (1/CU), WG=(bt:64 batch rows, ct:16 hidden cols).
// Waves: gp = wv&1 (gates {gp,gp+2}), kh = wv>>1 (K quarter of 128).

#define B_ 512
#define H_ 512
#define T_ 256
#define NWG 256
#define NTHR 512

typedef _Float16 half8_t __attribute__((ext_vector_type(8)));
typedef _Float16 half4_t __attribute__((ext_vector_type(4)));
typedef _Float16 half2_t __attribute__((ext_vector_type(2)));
typedef float floatx4 __attribute__((ext_vector_type(4)));

// ---- d_ws layout ----
#define W16_BYTES  (3u * 4u * H_ * H_ * 2u)     // 6 MiB f16 [W_hh0|W_ih1|W_hh1]
#define HBUF_ELEMS (B_ * H_)
#define HBUF_BYTES (HBUF_ELEMS * 2u)
#define H0_OFF   ((size_t)W16_BYTES)
#define H1_OFF   (H0_OFF + 2 * HBUF_BYTES)
#define BAR_OFF  (H1_OFF + 2 * HBUF_BYTES)
#define PART_OFF (BAR_OFF + 1024)

__device__ __forceinline__ float sigm_(float x) { return 1.0f / (1.0f + __expf(-x)); }
__device__ __forceinline__ float tanh_(float x) { return 1.0f - 2.0f / (1.0f + __expf(2.0f * x)); }

// ---------------- prep kernels ----------------
__global__ void prep_weights(const float* __restrict__ whh0,
                             const float* __restrict__ wih1,
                             const float* __restrict__ whh1,
                             _Float16* __restrict__ w16) {
    const int QM = (4 * H_ * H_) / 4;
    int i = blockIdx.x * blockDim.x + threadIdx.x;
    if (i >= 3 * QM) return;
    const float* src; int base;
    if (i < QM)          { src = whh0; base = 0; }
    else if (i < 2 * QM) { src = wih1; base = QM; }
    else                 { src = whh1; base = 2 * QM; }
    float4 v = ((const float4*)src)[i - base];
    half4_t h;
    h[0] = (_Float16)v.x; h[1] = (_Float16)v.y; h[2] = (_Float16)v.z; h[3] = (_Float16)v.w;
    ((half4_t*)w16)[i] = h;
}

__global__ void prep_state(const float* __restrict__ h_in,
                           _Float16* __restrict__ H0, _Float16* __restrict__ H1) {
    int i = blockIdx.x * blockDim.x + threadIdx.x;
    float4 a = ((const float4*)h_in)[i];
    float4 b = ((const float4*)h_in)[(B_ * H_) / 4 + i];
    half4_t ha, hb;
    ha[0] = (_Float16)a.x; ha[1] = (_Float16)a.y; ha[2] = (_Float16)a.z; ha[3] = (_Float16)a.w;
    hb[0] = (_Float16)b.x; hb[1] = (_Float16)b.y; hb[2] = (_Float16)b.z; hb[3] = (_Float16)b.w;
    ((half4_t*)H0)[i] = ha;
    ((half4_t*)H1)[i] = hb;
}

// ---------------- helpers ----------------
// global->LDS 16B, aux=0x11 (SC0|SC1: bypass L1/L2, read L3-coherent data)
#define GLL16(gp, lp) __builtin_amdgcn_global_load_lds( \
    (const __attribute__((address_space(1))) unsigned int*)(gp), \
    (__attribute__((address_space(3))) unsigned int*)(lp), 16, 0, 0x11)

#define WAITV(N) asm volatile("s_waitcnt vmcnt(" #N ")" ::: "memory")

// Stage a 64x512 f16 tile, row-interleaved: wave wv's i-th GLL stages row
// i*8+wv, so all waves' first 2k GLLs cover rows [0,16k) -> counted vmcnt
// mini-phases work. Source pre-XOR-swizzled per 16B granule.
__device__ __forceinline__ void stage_rows_il(const char* gsrc, char* lbuf, int wv, int lane) {
#pragma unroll
    for (int i = 0; i < 8; ++i) {
        int row = i * 8 + wv;
        const char* gp = gsrc + row * 1024 + (((lane ^ (row & 7)) & 63) << 4);
        GLL16(gp, lbuf + row * 1024);
    }
}

// ---------------- main persistent kernel ----------------
__launch_bounds__(NTHR)
__global__ void lstm_decode(
    const float* __restrict__ c_in,
    const float* __restrict__ wih0, const float* __restrict__ bih0,
    const float* __restrict__ bhh0,
    const float* __restrict__ bih1, const float* __restrict__ bhh1,
    const float* __restrict__ fcw, const float* __restrict__ fcb,
    const _Float16* __restrict__ w16,
    _Float16* __restrict__ Hs0, _Float16* __restrict__ Hs1,
    int* __restrict__ bar, float* __restrict__ part,
    float* __restrict__ outp)
{
    __shared__ __align__(16) char bufA[65536];   // h1 tile
    __shared__ __align__(16) char bufB[65536];   // h0 tile (persists across step)
    __shared__ float gbuf[4][64][20];            // gate accumulate (ds_add), 2-way
    __shared__ float xrow[64];

    const int tid  = (int)threadIdx.x;
    const int lane = tid & 63;
    const int wv   = tid >> 6;    // 0..7
    const int gp   = wv & 1;      // gate pair -> gates {gp, gp+2}
    const int kh   = wv >> 1;     // K quarter (128 wide)
    const int cl   = lane & 15;
    const int kg   = lane >> 4;   // 0..3
    const int bt   = (int)blockIdx.x & 7;
    const int ct   = (int)blockIdx.x >> 3;

    // ---- persistent weight fragments: wfX[g][ksg], gate = gp+2*g ----
    half8_t wf0[2][4], wf1[2][4], wf2[2][4];
    float b0v[2], b1v[2], wxv[2];
#pragma unroll
    for (int g = 0; g < 2; ++g) {
        const int n = (gp + 2 * g) * H_ + ct * 16 + cl;
        const _Float16* r0 = w16 + (size_t)n * H_ + kh * 128 + kg * 8;
        const _Float16* r1 = r0 + 4 * H_ * H_;
        const _Float16* r2 = r0 + 8 * H_ * H_;
#pragma unroll
        for (int ksg = 0; ksg < 4; ++ksg) {
            wf0[g][ksg] = *(const half8_t*)(r0 + ksg * 32);
            wf1[g][ksg] = *(const half8_t*)(r1 + ksg * 32);
            wf2[g][ksg] = *(const half8_t*)(r2 + ksg * 32);
        }
        b0v[g] = bih0[n] + bhh0[n];
        b1v[g] = bih1[n] + bhh1[n];
        wxv[g] = wih0[n];
    }
    const float fcb0 = fcb[0];

    // ---- elementwise domain: thread owns (erow, ecol..ecol+1) ----
    const int erow = tid >> 3;
    const int ecol = (tid & 7) * 2;
    float c0a, c0b, c1a, c1b;
    {
        size_t base0 = (size_t)(bt * 64 + erow) * H_ + ct * 16 + ecol;
        c0a = c_in[base0];                     c0b = c_in[base0 + 1];
        c1a = c_in[(size_t)B_ * H_ + base0];   c1b = c_in[(size_t)B_ * H_ + base0 + 1];
    }
    const float2 fcv = *(const float2*)(fcw + ct * 16 + ecol);

    // A-fragment addressing: row = mt*16+cl, k = kh*128 + ksg*32 + kg*8
    const int abase = cl * 1024 + kh * 256 + kg * 16;
    const int axor  = (cl & 7) << 4;

    int* flagg   = bar + bt * 32;
    float* partg = part + bt * 2048;   // [64 rows][32 ct]
    int ep = 0;

    // ---- prologue ----
    for (int i = tid; i < 4 * 64 * 20; i += NTHR) ((float*)gbuf)[i] = 0.f;
    if (tid < 64) xrow[tid] = 0.f;
    stage_rows_il((const char*)Hs0 + (size_t)bt * 64 * 1024, bufB, wv, lane);
    __syncthreads();   // drains GLLs + makes gbuf zeros visible

    floatx4 accG0[2][4], accG1[2][4];

    for (int t = 0; t < T_; ++t) {
        const char* h1r = (const char*)Hs1 + (size_t)(t & 1) * HBUF_BYTES + (size_t)bt * 64 * 1024;
        _Float16* h0w = Hs0 + (size_t)((t + 1) & 1) * HBUF_ELEMS;
        _Float16* h1w = Hs1 + (size_t)((t + 1) & 1) * HBUF_ELEMS;

        // ======== phase A ========
        // x-partial loads first (so their wait doesn't drain the stage GLLs)
        float s0 = 0.f, s1 = 0.f, s2 = 0.f, s3 = 0.f;
        if (t > 0) {
            const float* pb = partg + (tid >> 3) * 32 + (tid & 7) * 4;
            s0 = __hip_atomic_load(pb + 0, __ATOMIC_RELAXED, __HIP_MEMORY_SCOPE_AGENT);
            s1 = __hip_atomic_load(pb + 1, __ATOMIC_RELAXED, __HIP_MEMORY_SCOPE_AGENT);
            s2 = __hip_atomic_load(pb + 2, __ATOMIC_RELAXED, __HIP_MEMORY_SCOPE_AGENT);
            s3 = __hip_atomic_load(pb + 3, __ATOMIC_RELAXED, __HIP_MEMORY_SCOPE_AGENT);
        }
        stage_rows_il(h1r, bufA, wv, lane);   // h1 -> bufA (overlaps PASS0)
        if (t > 0) {
            float xs = (s0 + s1) + (s2 + s3);
            xs += __shfl_xor(xs, 1);
            xs += __shfl_xor(xs, 2);
            xs += __shfl_xor(xs, 4);
            xs += fcb0;
            if ((tid & 7) == 0) {
                xrow[tid >> 3] = xs;
                if (ct == 0) outp[(size_t)(bt * 64 + (tid >> 3)) * T_ + (t - 1)] = xs;
            }
        }
#pragma unroll
        for (int g = 0; g < 2; ++g)
#pragma unroll
            for (int mt = 0; mt < 4; ++mt) {
                accG0[g][mt] = (floatx4)0.f;
                accG1[g][mt] = (floatx4)0.f;
            }

        // PASS0: G0 += h0(bufB) x W_hh0^T   (bufB resident from prev step)
#pragma unroll
        for (int mt = 0; mt < 4; ++mt)
#pragma unroll
            for (int ksg = 0; ksg < 4; ++ksg) {
                int a_ = (abase + mt * 16384 + ksg * 64) ^ axor;
                half8_t av = *(const half8_t*)(bufB + a_);
#pragma unroll
                for (int g = 0; g < 2; ++g)
                    accG0[g][mt] = __builtin_amdgcn_mfma_f32_16x16x32_f16(av, wf0[g][ksg], accG0[g][mt], 0, 0, 0);
            }
        asm volatile("s_waitcnt vmcnt(0) lgkmcnt(0)\n\ts_barrier" ::: "memory");
        // PASS2: G1 += h1(bufA) x W_hh1^T
#pragma unroll
        for (int mt = 0; mt < 4; ++mt)
#pragma unroll
            for (int ksg = 0; ksg < 4; ++ksg) {
                int a_ = (abase + mt * 16384 + ksg * 64) ^ axor;
                half8_t av = *(const half8_t*)(bufA + a_);
#pragma unroll
                for (int g = 0; g < 2; ++g)
                    accG1[g][mt] = __builtin_amdgcn_mfma_f32_16x16x32_f16(av, wf2[g][ksg], accG1[g][mt], 0, 0, 0);
            }

        // exchange G0 (bias + x injected once, by kh==0 waves)
        if (kh == 0) {
#pragma unroll
            for (int g = 0; g < 2; ++g)
#pragma unroll
                for (int mt = 0; mt < 4; ++mt)
#pragma unroll
                    for (int r = 0; r < 4; ++r)
                        accG0[g][mt][r] += __builtin_fmaf(xrow[mt * 16 + kg * 4 + r], wxv[g], b0v[g]);
        }
#pragma unroll
        for (int g = 0; g < 2; ++g)
#pragma unroll
            for (int mt = 0; mt < 4; ++mt)
#pragma unroll
                for (int r = 0; r < 4; ++r)
                    atomicAdd(&gbuf[gp + 2 * g][mt * 16 + kg * 4 + r][cl], accG0[g][mt][r]);
        __syncthreads();
        // EW layer 0 (+ zero-restore gbuf)
        {
            float2 iv = *(const float2*)&gbuf[0][erow][ecol];
            float2 fv = *(const float2*)&gbuf[1][erow][ecol];
            float2 gv = *(const float2*)&gbuf[2][erow][ecol];
            float2 ov = *(const float2*)&gbuf[3][erow][ecol];
            float2 z; z.x = 0.f; z.y = 0.f;
            *(float2*)&gbuf[0][erow][ecol] = z;
            *(float2*)&gbuf[1][erow][ecol] = z;
            *(float2*)&gbuf[2][erow][ecol] = z;
            *(float2*)&gbuf[3][erow][ecol] = z;
            float ca = sigm_(fv.x) * c0a + sigm_(iv.x) * tanh_(gv.x);
            float cb = sigm_(fv.y) * c0b + sigm_(iv.y) * tanh_(gv.y);
            c0a = ca; c0b = cb;
            half2_t hh;
            hh[0] = (_Float16)(sigm_(ov.x) * tanh_(ca));
            hh[1] = (_Float16)(sigm_(ov.y) * tanh_(cb));
            unsigned int u = __builtin_bit_cast(unsigned int, hh);
            unsigned int* dst = (unsigned int*)(h0w + (size_t)(bt * 64 + erow) * H_ + ct * 16 + ecol);
            __hip_atomic_store(dst, u, __ATOMIC_RELAXED, __HIP_MEMORY_SCOPE_AGENT);
        }
        // ---- barrier A ----
        ++ep;
        __syncthreads();   // drains vmcnt (h0_new stores) for every wave
        if (wv == 0) {
            if (lane == 0)
                __hip_atomic_store(&flagg[ct], ep, __ATOMIC_RELAXED, __HIP_MEMORY_SCOPE_AGENT);
            for (;;) {
                int v = __hip_atomic_load(&flagg[lane & 31], __ATOMIC_RELAXED, __HIP_MEMORY_SCOPE_AGENT);
                if (__all(v >= ep)) break;
            }
        }
        __syncthreads();

        // ======== phase B ========
        // stage h0_new -> bufB, row-interleaved; overlap drain with PASS1
        stage_rows_il((const char*)h0w + (size_t)bt * 64 * 1024, bufB, wv, lane);
#define MT_CHUNK(MT, VN)                                                      \
        WAITV(VN);                                                            \
        __builtin_amdgcn_s_barrier();                                         \
        _Pragma("unroll")                                                     \
        for (int ksg = 0; ksg < 4; ++ksg) {                                   \
            int a_ = (abase + (MT) * 16384 + ksg * 64) ^ axor;                \
            half8_t av = *(const half8_t*)(bufB + a_);                        \
            _Pragma("unroll")                                                 \
            for (int g = 0; g < 2; ++g)                                       \
                accG1[g][MT] = __builtin_amdgcn_mfma_f32_16x16x32_f16(        \
                    av, wf1[g][ksg], accG1[g][MT], 0, 0, 0);                  \
        }
        MT_CHUNK(0, 6)
        MT_CHUNK(1, 4)
        MT_CHUNK(2, 2)
        MT_CHUNK(3, 0)
#undef MT_CHUNK

        // exchange G1 (bias by kh==0)
        if (kh == 0) {
#pragma unroll
            for (int g = 0; g < 2; ++g)
#pragma unroll
                for (int mt = 0; mt < 4; ++mt)
#pragma unroll
                    for (int r = 0; r < 4; ++r)
                        accG1[g][mt][r] += b1v[g];
        }
#pragma unroll
        for (int g = 0; g < 2; ++g)
#pragma unroll
            for (int mt = 0; mt < 4; ++mt)
#pragma unroll
                for (int r = 0; r < 4; ++r)
                    atomicAdd(&gbuf[gp + 2 * g][mt * 16 + kg * 4 + r][cl], accG1[g][mt][r]);
        __syncthreads();
        // EW layer 1 + FC partial (+ zero-restore)
        {
            float2 iv = *(const float2*)&gbuf[0][erow][ecol];
            float2 fv = *(const float2*)&gbuf[1][erow][ecol];
            float2 gv = *(const float2*)&gbuf[2][erow][ecol];
            float2 ov = *(const float2*)&gbuf[3][erow][ecol];
            float2 z; z.x = 0.f; z.y = 0.f;
            *(float2*)&gbuf[0][erow][ecol] = z;
            *(float2*)&gbuf[1][erow][ecol] = z;
            *(float2*)&gbuf[2][erow][ecol] = z;
            *(float2*)&gbuf[3][erow][ecol] = z;
            float ca = sigm_(fv.x) * c1a + sigm_(iv.x) * tanh_(gv.x);
            float cb = sigm_(fv.y) * c1b + sigm_(iv.y) * tanh_(gv.y);
            c1a = ca; c1b = cb;
            float ha = sigm_(ov.x) * tanh_(ca);
            float hb = sigm_(ov.y) * tanh_(cb);
            half2_t hh; hh[0] = (_Float16)ha; hh[1] = (_Float16)hb;
            unsigned int u = __builtin_bit_cast(unsigned int, hh);
            unsigned int* dst = (unsigned int*)(h1w + (size_t)(bt * 64 + erow) * H_ + ct * 16 + ecol);
            __hip_atomic_store(dst, u, __ATOMIC_RELAXED, __HIP_MEMORY_SCOPE_AGENT);
            float ps = __builtin_fmaf(ha, fcv.x, hb * fcv.y);
            ps += __shfl_xor(ps, 1);
            ps += __shfl_xor(ps, 2);
            ps += __shfl_xor(ps, 4);
            if ((tid & 7) == 0)
                __hip_atomic_store(&partg[erow * 32 + ct], ps, __ATOMIC_RELAXED, __HIP_MEMORY_SCOPE_AGENT);
        }
        // ---- barrier B ----
        ++ep;
        __syncthreads();
        if (wv == 0) {
            if (lane == 0)
                __hip_atomic_store(&flagg[ct], ep, __ATOMIC_RELAXED, __HIP_MEMORY_SCOPE_AGENT);
            for (;;) {
                int v = __hip_atomic_load(&flagg[lane & 31], __ATOMIC_RELAXED, __HIP_MEMORY_SCOPE_AGENT);
                if (__all(v >= ep)) break;
            }
        }
        __syncthreads();
    }

    // epilogue: final x -> outp column T_-1
    if (ct == 0) {
        const float* pb = partg + (tid >> 3) * 32 + (tid & 7) * 4;
        float s0 = __hip_atomic_load(pb + 0, __ATOMIC_RELAXED, __HIP_MEMORY_SCOPE_AGENT);
        float s1 = __hip_atomic_load(pb + 1, __ATOMIC_RELAXED, __HIP_MEMORY_SCOPE_AGENT);
        float s2 = __hip_atomic_load(pb + 2, __ATOMIC_RELAXED, __HIP_MEMORY_SCOPE_AGENT);
        float s3 = __hip_atomic_load(pb + 3, __ATOMIC_RELAXED, __HIP_MEMORY_SCOPE_AGENT);
        float xs = (s0 + s1) + (s2 + s3);
        xs += __shfl_xor(xs, 1);
        xs += __shfl_xor(xs, 2);
        xs += __shfl_xor(xs, 4);
        xs += fcb0;
        if ((tid & 7) == 0)
            outp[(size_t)(bt * 64 + (tid >> 3)) * T_ + (T_ - 1)] = xs;
    }
}

extern "C" void kernel_launch(void* const* d_in, const int* in_sizes, int n_in,
                              void* d_out, int out_size, void* d_ws, size_t ws_size,
                              hipStream_t stream) {
    const float* h_in = (const float*)d_in[0];
    const float* c_in = (const float*)d_in[1];
    const float* wih0 = (const float*)d_in[2];
    const float* whh0 = (const float*)d_in[3];
    const float* bih0 = (const float*)d_in[4];
    const float* bhh0 = (const float*)d_in[5];
    const float* wih1 = (const float*)d_in[6];
    const float* whh1 = (const float*)d_in[7];
    const float* bih1 = (const float*)d_in[8];
    const float* bhh1 = (const float*)d_in[9];
    const float* fcw  = (const float*)d_in[10];
    const float* fcb  = (const float*)d_in[11];
    float* out = (float*)d_out;

    char* ws = (char*)d_ws;
    _Float16* w16 = (_Float16*)ws;
    _Float16* Hs0 = (_Float16*)(ws + H0_OFF);
    _Float16* Hs1 = (_Float16*)(ws + H1_OFF);
    int* bar      = (int*)(ws + BAR_OFF);
    float* part   = (float*)(ws + PART_OFF);

    (void)hipMemsetAsync(bar, 0, 1024, stream);

    {
        const int n4 = 3 * (4 * H_ * H_) / 4;
        prep_weights<<<(n4 + 255) / 256, 256, 0, stream>>>(whh0, wih1, whh1, w16);
    }
    prep_state<<<(B_ * H_ / 4) / 256, 256, 0, stream>>>(h_in, Hs0, Hs1);

    lstm_decode<<<NWG, NTHR, 0, stream>>>(c_in, wih0, bih0, bhh0, bih1, bhh1,
                                          fcw, fcb, w16, Hs0, Hs1, bar, part, out);
}

// Round 6
// 2419.062 us; speedup vs baseline: 5.3565x; 5.3565x over previous
//
#include <hip/hip_runtime.h>
#include <hip/hip_bf16.h>

// MomentumDecoder: 2-layer LSTM (B=512,H=512), 256 autoregressive steps.
// Round 6: round-4 skeleton + XCD-local groups (single delta).
// Groups formed by hardware XCD id (s_getreg HW_REG_XCC_ID) + per-XCD rank:
// exactly 32 WGs/XCD (LDS forces 1 WG/CU, grid=256=CUs). All cross-WG data
// (h-state, FC partials) moves through the XCD's own L2: plain stores
// (write-through to L2) + sc0-only loads (L1 bypass). Flags stay agent-scope.

#define B_ 512
#define H_ 512
#define T_ 256
#define NWG 256
#define NTHR 512

typedef _Float16 half8_t __attribute__((ext_vector_type(8)));
typedef _Float16 half4_t __attribute__((ext_vector_type(4)));
typedef _Float16 half2_t __attribute__((ext_vector_type(2)));
typedef float floatx4 __attribute__((ext_vector_type(4)));

// ---- d_ws layout ----
#define W16_BYTES  (3u * 4u * H_ * H_ * 2u)     // 6 MiB f16 [W_hh0|W_ih1|W_hh1]
#define HBUF_ELEMS (B_ * H_)
#define HBUF_BYTES (HBUF_ELEMS * 2u)
#define H0_OFF   ((size_t)W16_BYTES)
#define H1_OFF   (H0_OFF + 2 * HBUF_BYTES)
#define BAR_OFF  (H1_OFF + 2 * HBUF_BYTES)      // 256 flag ints + 8 rank ints
#define PART_OFF (BAR_OFF + 2048)

__device__ __forceinline__ float sigm_(float x) { return 1.0f / (1.0f + __expf(-x)); }
__device__ __forceinline__ float tanh_(float x) { return 1.0f - 2.0f / (1.0f + __expf(2.0f * x)); }

// ---------------- prep kernels ----------------
__global__ void prep_weights(const float* __restrict__ whh0,
                             const float* __restrict__ wih1,
                             const float* __restrict__ whh1,
                             _Float16* __restrict__ w16) {
    const int QM = (4 * H_ * H_) / 4;
    int i = blockIdx.x * blockDim.x + threadIdx.x;
    if (i >= 3 * QM) return;
    const float* src; int base;
    if (i < QM)          { src = whh0; base = 0; }
    else if (i < 2 * QM) { src = wih1; base = QM; }
    else                 { src = whh1; base = 2 * QM; }
    float4 v = ((const float4*)src)[i - base];
    half4_t h;
    h[0] = (_Float16)v.x; h[1] = (_Float16)v.y; h[2] = (_Float16)v.z; h[3] = (_Float16)v.w;
    ((half4_t*)w16)[i] = h;
}

__global__ void prep_state(const float* __restrict__ h_in,
                           _Float16* __restrict__ H0, _Float16* __restrict__ H1) {
    int i = blockIdx.x * blockDim.x + threadIdx.x;
    float4 a = ((const float4*)h_in)[i];
    float4 b = ((const float4*)h_in)[(B_ * H_) / 4 + i];
    half4_t ha, hb;
    ha[0] = (_Float16)a.x; ha[1] = (_Float16)a.y; ha[2] = (_Float16)a.z; ha[3] = (_Float16)a.w;
    hb[0] = (_Float16)b.x; hb[1] = (_Float16)b.y; hb[2] = (_Float16)b.z; hb[3] = (_Float16)b.w;
    ((half4_t*)H0)[i] = ha;
    ((half4_t*)H1)[i] = hb;
}

// ---------------- helpers ----------------
// global->LDS 16B, aux=0x01 (SC0: L1 bypass; served from the XCD's L2, which
// is coherent with same-XCD producers' plain write-through stores)
#define GLL16(gp, lp) __builtin_amdgcn_global_load_lds( \
    (const __attribute__((address_space(1))) unsigned int*)(gp), \
    (__attribute__((address_space(3))) unsigned int*)(lp), 16, 0, 0x01)

// Stage this wave's 8 rows of a 64x512 f16 tile; source pre-XOR-swizzled so
// linear LDS writes match the ^((row&7)<<4) ds_read swizzle.
__device__ __forceinline__ void stage_rows(const char* gsrc, char* lbuf, int wv, int lane) {
#pragma unroll
    for (int i = 0; i < 8; ++i) {
        int row = wv * 8 + i;
        const char* gp = gsrc + row * 1024 + (((lane ^ (row & 7)) & 63) << 4);
        GLL16(gp, lbuf + row * 1024);
    }
}

// sc0-only 16B load (L1 bypass, L2-served). Value must be consumed only after
// the tied s_waitcnt asm below ("+v" makes the use depend on the post-wait reg).
__device__ __forceinline__ floatx4 load16_sc0(const float* p) {
    floatx4 v;
    asm volatile("global_load_dwordx4 %0, %1, off sc0" : "=v"(v) : "v"(p) : "memory");
    return v;
}

#define PASS(bufc, wf, acc) do {                                              \
    _Pragma("unroll")                                                         \
    for (int ksg = 0; ksg < 8; ++ksg) {                                       \
        _Pragma("unroll")                                                     \
        for (int mt = 0; mt < 4; ++mt) {                                      \
            int a_ = (abase + mt * 16384 + ksg * 64) ^ axor;                  \
            half8_t av_ = *(const half8_t*)((bufc) + a_);                     \
            acc[mt] = __builtin_amdgcn_mfma_f32_16x16x32_f16(av_, (wf)[ksg],  \
                                                             acc[mt], 0, 0, 0); \
        }                                                                     \
    }                                                                         \
} while (0)

// ---------------- main persistent kernel ----------------
__launch_bounds__(NTHR)
__global__ void lstm_decode(
    const float* __restrict__ c_in,
    const float* __restrict__ wih0, const float* __restrict__ bih0,
    const float* __restrict__ bhh0,
    const float* __restrict__ bih1, const float* __restrict__ bhh1,
    const float* __restrict__ fcw, const float* __restrict__ fcb,
    const _Float16* __restrict__ w16,
    _Float16* __restrict__ Hs0, _Float16* __restrict__ Hs1,
    int* __restrict__ bar, float* __restrict__ part,
    float* __restrict__ outp)
{
    __shared__ __align__(16) char bufA[65536];   // h1 tile (phase A)
    __shared__ __align__(16) char bufB[65536];   // h0 tile (persists A->B->next A)
    __shared__ float gbuf[4][64][20];            // gate exchange, padded
    __shared__ float xrow[64];
    __shared__ int sh_bt, sh_ct;

    const int tid  = (int)threadIdx.x;
    const int lane = tid & 63;
    const int wv   = tid >> 6;    // 0..7
    const int g    = wv & 3;      // gate (i,f,g,o)
    const int kh   = wv >> 2;     // K half
    const int cl   = lane & 15;
    const int kg   = lane >> 4;   // 0..3

    // ---- dynamic XCD-local group formation ----
    if (tid == 0) {
        unsigned int xcc;
        asm volatile("s_getreg_b32 %0, hwreg(HW_REG_XCC_ID)" : "=s"(xcc));
        int mybt = (int)(xcc & 7u);
        int rank = atomicAdd(&bar[256 + mybt], 1);   // agent-scope
        sh_bt = mybt;
        sh_ct = rank & 31;
    }
    __syncthreads();
    const int bt = sh_bt;
    const int ct = sh_ct;

    // ---- persistent weight fragments ----
    const int n = g * H_ + ct * 16 + cl;
    half8_t wf0[8], wf1[8], wf2[8];
    {
        const _Float16* r0 = w16 + (size_t)n * H_ + kh * 256 + kg * 8;
        const _Float16* r1 = r0 + 4 * H_ * H_;
        const _Float16* r2 = r0 + 8 * H_ * H_;
#pragma unroll
        for (int ksg = 0; ksg < 8; ++ksg) {
            wf0[ksg] = *(const half8_t*)(r0 + ksg * 32);
            wf1[ksg] = *(const half8_t*)(r1 + ksg * 32);
            wf2[ksg] = *(const half8_t*)(r2 + ksg * 32);
        }
    }
    const float b0   = bih0[n] + bhh0[n];
    const float b1   = bih1[n] + bhh1[n];
    const float wx   = wih0[n];
    const float fcb0 = fcb[0];

    // ---- elementwise domain ----
    const int erow = tid >> 3;
    const int ecol = (tid & 7) * 2;
    float c0a, c0b, c1a, c1b;
    {
        size_t base0 = (size_t)(bt * 64 + erow) * H_ + ct * 16 + ecol;
        c0a = c_in[base0];                     c0b = c_in[base0 + 1];
        c1a = c_in[(size_t)B_ * H_ + base0];   c1b = c_in[(size_t)B_ * H_ + base0 + 1];
    }
    const float2 fcv = *(const float2*)(fcw + ct * 16 + ecol);

    const int abase = cl * 1024 + kh * 512 + kg * 16;
    const int axor  = (cl & 7) << 4;

    int* flagg   = bar + bt * 32;
    float* partg = part + bt * 2048;   // [64 rows][32 ct]
    int ep = 0;

    if (tid < 64) xrow[tid] = 0.f;
    // prologue: stage initial h0 into bufB
    stage_rows((const char*)Hs0 + (size_t)bt * 64 * 1024, bufB, wv, lane);

    floatx4 accG0[4], accG1[4];

    for (int t = 0; t < T_; ++t) {
        const char* h1r = (const char*)Hs1 + (size_t)(t & 1) * HBUF_BYTES + (size_t)bt * 64 * 1024;
        _Float16* h0w = Hs0 + (size_t)((t + 1) & 1) * HBUF_ELEMS;
        _Float16* h1w = Hs1 + (size_t)((t + 1) & 1) * HBUF_ELEMS;

        // ======== phase A ========
        floatx4 pv;
        if (t > 0)   // issue FC-partial load (1 VMEM) before the 8 stage GLLs
            pv = load16_sc0(partg + (tid >> 3) * 32 + (tid & 7) * 4);
        stage_rows(h1r, bufA, wv, lane);          // h1 -> bufA (overlaps PASS0)
        if (t > 0) {
            // wait until only the 8 GLLs are outstanding -> pv is complete
            asm volatile("s_waitcnt vmcnt(8)" : "+v"(pv) :: "memory");
            float xs = (pv[0] + pv[1]) + (pv[2] + pv[3]);
            xs += __shfl_xor(xs, 1);
            xs += __shfl_xor(xs, 2);
            xs += __shfl_xor(xs, 4);
            xs += fcb0;
            if ((tid & 7) == 0) {
                xrow[tid >> 3] = xs;
                if (ct == 0) outp[(size_t)(bt * 64 + (tid >> 3)) * T_ + (t - 1)] = xs;
            }
        }
        __syncthreads();                          // xrow visible

#pragma unroll
        for (int mt = 0; mt < 4; ++mt) {
            if (kh == 0) {
#pragma unroll
                for (int r = 0; r < 4; ++r) {
                    accG0[mt][r] = __builtin_fmaf(xrow[mt * 16 + kg * 4 + r], wx, b0);
                    accG1[mt][r] = b1;
                }
            } else {
#pragma unroll
                for (int r = 0; r < 4; ++r) { accG0[mt][r] = 0.f; accG1[mt][r] = 0.f; }
            }
        }
        if (t == 0)  // prologue bufB stage must be complete across all waves
            asm volatile("s_waitcnt vmcnt(0) lgkmcnt(0)\n\ts_barrier" ::: "memory");

        PASS(bufB, wf0, accG0);                   // h0 x W_hh0^T
        asm volatile("s_waitcnt vmcnt(0) lgkmcnt(0)\n\ts_barrier" ::: "memory");
        PASS(bufA, wf2, accG1);                   // h1 x W_hh1^T (partial)

        // gate0 exchange across kh halves
        if (kh == 0) {
#pragma unroll
            for (int mt = 0; mt < 4; ++mt)
#pragma unroll
                for (int r = 0; r < 4; ++r)
                    gbuf[g][mt * 16 + kg * 4 + r][cl] = accG0[mt][r];
        }
        __syncthreads();
        if (kh == 1) {
#pragma unroll
            for (int mt = 0; mt < 4; ++mt)
#pragma unroll
                for (int r = 0; r < 4; ++r)
                    gbuf[g][mt * 16 + kg * 4 + r][cl] += accG0[mt][r];
        }
        __syncthreads();
        // EW layer 0: plain store (write-through to local L2)
        {
            float2 iv = *(const float2*)&gbuf[0][erow][ecol];
            float2 fv = *(const float2*)&gbuf[1][erow][ecol];
            float2 gv = *(const float2*)&gbuf[2][erow][ecol];
            float2 ov = *(const float2*)&gbuf[3][erow][ecol];
            float ca = sigm_(fv.x) * c0a + sigm_(iv.x) * tanh_(gv.x);
            float cb = sigm_(fv.y) * c0b + sigm_(iv.y) * tanh_(gv.y);
            c0a = ca; c0b = cb;
            half2_t hh;
            hh[0] = (_Float16)(sigm_(ov.x) * tanh_(ca));
            hh[1] = (_Float16)(sigm_(ov.y) * tanh_(cb));
            *(half2_t*)(h0w + (size_t)(bt * 64 + erow) * H_ + ct * 16 + ecol) = hh;
        }
        // ---- barrier A ----
        ++ep;
        __syncthreads();   // drains vmcnt: h0_new stores visible in local L2
        if (wv == 0) {
            if (lane == 0)
                __hip_atomic_store(&flagg[ct], ep, __ATOMIC_RELAXED, __HIP_MEMORY_SCOPE_AGENT);
            for (;;) {
                int v = __hip_atomic_load(&flagg[lane & 31], __ATOMIC_RELAXED, __HIP_MEMORY_SCOPE_AGENT);
                if (__all(v >= ep)) break;
            }
        }
        __syncthreads();

        // ======== phase B ========
        stage_rows((const char*)h0w + (size_t)bt * 64 * 1024, bufB, wv, lane);
        asm volatile("s_waitcnt vmcnt(0) lgkmcnt(0)\n\ts_barrier" ::: "memory");
        PASS(bufB, wf1, accG1);                   // h0_new x W_ih1^T

        if (kh == 0) {
#pragma unroll
            for (int mt = 0; mt < 4; ++mt)
#pragma unroll
                for (int r = 0; r < 4; ++r)
                    gbuf[g][mt * 16 + kg * 4 + r][cl] = accG1[mt][r];
        }
        __syncthreads();
        if (kh == 1) {
#pragma unroll
            for (int mt = 0; mt < 4; ++mt)
#pragma unroll
                for (int r = 0; r < 4; ++r)
                    gbuf[g][mt * 16 + kg * 4 + r][cl] += accG1[mt][r];
        }
        __syncthreads();
        // EW layer 1 + FC partial (plain stores, local L2)
        {
            float2 iv = *(const float2*)&gbuf[0][erow][ecol];
            float2 fv = *(const float2*)&gbuf[1][erow][ecol];
            float2 gv = *(const float2*)&gbuf[2][erow][ecol];
            float2 ov = *(const float2*)&gbuf[3][erow][ecol];
            float ca = sigm_(fv.x) * c1a + sigm_(iv.x) * tanh_(gv.x);
            float cb = sigm_(fv.y) * c1b + sigm_(iv.y) * tanh_(gv.y);
            c1a = ca; c1b = cb;
            float ha = sigm_(ov.x) * tanh_(ca);
            float hb = sigm_(ov.y) * tanh_(cb);
            half2_t hh; hh[0] = (_Float16)ha; hh[1] = (_Float16)hb;
            *(half2_t*)(h1w + (size_t)(bt * 64 + erow) * H_ + ct * 16 + ecol) = hh;
            float ps = __builtin_fmaf(ha, fcv.x, hb * fcv.y);
            ps += __shfl_xor(ps, 1);
            ps += __shfl_xor(ps, 2);
            ps += __shfl_xor(ps, 4);
            if ((tid & 7) == 0)
                partg[erow * 32 + ct] = ps;
        }
        // ---- barrier B ----
        ++ep;
        __syncthreads();
        if (wv == 0) {
            if (lane == 0)
                __hip_atomic_store(&flagg[ct], ep, __ATOMIC_RELAXED, __HIP_MEMORY_SCOPE_AGENT);
            for (;;) {
                int v = __hip_atomic_load(&flagg[lane & 31], __ATOMIC_RELAXED, __HIP_MEMORY_SCOPE_AGENT);
                if (__all(v >= ep)) break;
            }
        }
        __syncthreads();
    }

    // epilogue: final x -> outp column T_-1
    if (ct == 0) {
        floatx4 pv = load16_sc0(partg + (tid >> 3) * 32 + (tid & 7) * 4);
        asm volatile("s_waitcnt vmcnt(0)" : "+v"(pv) :: "memory");
        float xs = (pv[0] + pv[1]) + (pv[2] + pv[3]);
        xs += __shfl_xor(xs, 1);
        xs += __shfl_xor(xs, 2);
        xs += __shfl_xor(xs, 4);
        xs += fcb0;
        if ((tid & 7) == 0)
            outp[(size_t)(bt * 64 + (tid >> 3)) * T_ + (T_ - 1)] = xs;
    }
}

extern "C" void kernel_launch(void* const* d_in, const int* in_sizes, int n_in,
                              void* d_out, int out_size, void* d_ws, size_t ws_size,
                              hipStream_t stream) {
    const float* h_in = (const float*)d_in[0];
    const float* c_in = (const float*)d_in[1];
    const float* wih0 = (const float*)d_in[2];
    const float* whh0 = (const float*)d_in[3];
    const float* bih0 = (const float*)d_in[4];
    const float* bhh0 = (const float*)d_in[5];
    const float* wih1 = (const float*)d_in[6];
    const float* whh1 = (const float*)d_in[7];
    const float* bih1 = (const float*)d_in[8];
    const float* bhh1 = (const float*)d_in[9];
    const float* fcw  = (const float*)d_in[10];
    const float* fcb  = (const float*)d_in[11];
    float* out = (float*)d_out;

    char* ws = (char*)d_ws;
    _Float16* w16 = (_Float16*)ws;
    _Float16* Hs0 = (_Float16*)(ws + H0_OFF);
    _Float16* Hs1 = (_Float16*)(ws + H1_OFF);
    int* bar      = (int*)(ws + BAR_OFF);
    float* part   = (float*)(ws + PART_OFF);

    // flags + rank counters must start at 0 (ws poisoned between calls)
    (void)hipMemsetAsync(bar, 0, 2048, stream);

    {
        const int n4 = 3 * (4 * H_ * H_) / 4;
        prep_weights<<<(n4 + 255) / 256, 256, 0, stream>>>(whh0, wih1, whh1, w16);
    }
    prep_state<<<(B_ * H_ / 4) / 256, 256, 0, stream>>>(h_in, Hs0, Hs1);

    lstm_decode<<<NWG, NTHR, 0, stream>>>(c_in, wih0, bih0, bhh0, bih1, bhh1,
                                          fcw, fcb, w16, Hs0, Hs1, bar, part, out);
}